// Round 3
// baseline (120.712 us; speedup 1.0000x reference)
//
#include <hip/hip_runtime.h>
#include <hip/hip_bf16.h>

#define BB 16
#define NQ 64
#define NK 512
#define HD 256   // H = QS = KS = VD = 256

typedef __attribute__((ext_vector_type(8))) short short8;
typedef __attribute__((ext_vector_type(4))) float f32x4;

__device__ __forceinline__ ushort bf16_rne(float v) {
    unsigned u = __float_as_uint(v);
    return (ushort)((u + 0x7FFFu + ((u >> 16) & 1u)) >> 16);
}
__device__ __forceinline__ float bf16_to_f(ushort h) {
    return __uint_as_float(((unsigned)h) << 16);
}

// ---------------------------------------------------------------------------
// W-only conversion (tiny): W fp32 [k][n] -> hi/lo bf16 TRANSPOSED [n][k].
// ---------------------------------------------------------------------------
__global__ __launch_bounds__(256) void wconv(
    const float* __restrict__ wq, const float* __restrict__ wk,
    ushort* __restrict__ wqh, ushort* __restrict__ wql,
    ushort* __restrict__ wkh, ushort* __restrict__ wkl)
{
    int widx = blockIdx.x * 256 + threadIdx.x;     // 0..32767
    const float* W; ushort *wh, *wl;
    if (widx < 16384) { W = wq; wh = wqh; wl = wql; }
    else { W = wk; wh = wkh; wl = wkl; widx -= 16384; }
    int n  = widx >> 6;
    int k4 = (widx & 63) * 4;
    ushort hh[4], ll[4];
    #pragma unroll
    for (int c = 0; c < 4; ++c) {
        float v = W[(k4 + c) * 256 + n];
        hh[c] = bf16_rne(v);
        ll[c] = bf16_rne(v - bf16_to_f(hh[c]));
    }
    *(ushort4*)&wh[n * 256 + k4] = make_ushort4(hh[0], hh[1], hh[2], hh[3]);
    *(ushort4*)&wl[n * 256 + k4] = make_ushort4(ll[0], ll[1], ll[2], ll[3]);
}

// ---------------------------------------------------------------------------
// Projection GEMM with FUSED A-conversion (unchanged from round 2).
// epilogue: exp2(acc*scale) so score kernel consumes EQ=e^{2q}, EK=e^{2k}.
// ---------------------------------------------------------------------------
__global__ __launch_bounds__(256, 2) void proj_fused(
    const float* __restrict__ queries, const float* __restrict__ keys,
    const ushort* __restrict__ wqh, const ushort* __restrict__ wql,
    const ushort* __restrict__ wkh, const ushort* __restrict__ wkl,
    float* __restrict__ qp, float* __restrict__ kp, float scale)
{
    __shared__ ushort AsH[64 * 64], AsL[64 * 64];
    __shared__ ushort BsH[64 * 64], BsL[64 * 64];

    const float* A; const ushort *Bh, *Bl; float* C; int rows0;
    const int bx = blockIdx.x;
    if (bx < 16) { A = queries; Bh = wqh; Bl = wql; C = qp; rows0 = bx * 64; }
    else         { A = keys;    Bh = wkh; Bl = wkl; C = kp; rows0 = (bx - 16) * 64; }
    const int cols0 = blockIdx.y * 64;

    const int t = threadIdx.x, lane = t & 63, wave = t >> 6;
    const int quad = lane >> 4, l15 = lane & 15;
    const int sr  = t >> 2;
    const int sc2 = (t & 3) * 2;

    f32x4 acc[4];
    #pragma unroll
    for (int j = 0; j < 4; ++j) acc[j] = (f32x4){0.f, 0.f, 0.f, 0.f};

    for (int k0 = 0; k0 < 256; k0 += 64) {
        const float* arow = &A[(size_t)(rows0 + sr) * 256 + k0 + sc2 * 8];
        float4 a0 = *(const float4*)&arow[0];
        float4 a1 = *(const float4*)&arow[4];
        float4 a2 = *(const float4*)&arow[8];
        float4 a3 = *(const float4*)&arow[12];
        const ushort* bhp = &Bh[(size_t)(cols0 + sr) * 256 + k0 + sc2 * 8];
        const ushort* blp = &Bl[(size_t)(cols0 + sr) * 256 + k0 + sc2 * 8];
        short8 b0h = *(const short8*)&bhp[0];
        short8 b1h = *(const short8*)&bhp[8];
        short8 b0l = *(const short8*)&blp[0];
        short8 b1l = *(const short8*)&blp[8];

        __syncthreads();

        float av[16] = {a0.x, a0.y, a0.z, a0.w, a1.x, a1.y, a1.z, a1.w,
                        a2.x, a2.y, a2.z, a2.w, a3.x, a3.y, a3.z, a3.w};
        short8 ah0, ah1, al0, al1;
        #pragma unroll
        for (int e = 0; e < 8; ++e) {
            ushort h0 = bf16_rne(av[e]);
            ushort h1 = bf16_rne(av[8 + e]);
            ah0[e] = (short)h0;
            ah1[e] = (short)h1;
            al0[e] = (short)bf16_rne(av[e] - bf16_to_f(h0));
            al1[e] = (short)bf16_rne(av[8 + e] - bf16_to_f(h1));
        }
        {
            int s0 = sr * 8 + ((sc2 + 0) ^ (sr & 7));
            int s1 = sr * 8 + ((sc2 + 1) ^ (sr & 7));
            *(short8*)&AsH[s0 * 8] = ah0;
            *(short8*)&AsH[s1 * 8] = ah1;
            *(short8*)&AsL[s0 * 8] = al0;
            *(short8*)&AsL[s1 * 8] = al1;
            *(short8*)&BsH[s0 * 8] = b0h;
            *(short8*)&BsH[s1 * 8] = b1h;
            *(short8*)&BsL[s0 * 8] = b0l;
            *(short8*)&BsL[s1 * 8] = b1l;
        }
        __syncthreads();

        #pragma unroll
        for (int ks = 0; ks < 2; ++ks) {
            const int c = ks * 4 + quad;
            short8 aH, aL, bH[4], bL[4];
            {
                int r = wave * 16 + l15;
                int slot = r * 8 + (c ^ (r & 7));
                aH = *(const short8*)&AsH[slot * 8];
                aL = *(const short8*)&AsL[slot * 8];
            }
            #pragma unroll
            for (int ns = 0; ns < 4; ++ns) {
                int n = ns * 16 + l15;
                int slot = n * 8 + (c ^ (n & 7));
                bH[ns] = *(const short8*)&BsH[slot * 8];
                bL[ns] = *(const short8*)&BsL[slot * 8];
            }
            #pragma unroll
            for (int ns = 0; ns < 4; ++ns)
                acc[ns] = __builtin_amdgcn_mfma_f32_16x16x32_bf16(aH, bH[ns], acc[ns], 0, 0, 0);
            #pragma unroll
            for (int ns = 0; ns < 4; ++ns)
                acc[ns] = __builtin_amdgcn_mfma_f32_16x16x32_bf16(aL, bH[ns], acc[ns], 0, 0, 0);
            #pragma unroll
            for (int ns = 0; ns < 4; ++ns)
                acc[ns] = __builtin_amdgcn_mfma_f32_16x16x32_bf16(aH, bL[ns], acc[ns], 0, 0, 0);
        }
    }

    const int rbase = rows0 + wave * 16 + quad * 4;
    #pragma unroll
    for (int ns = 0; ns < 4; ++ns) {
        int col = cols0 + ns * 16 + l15;
        #pragma unroll
        for (int r = 0; r < 4; ++r)
            C[(size_t)(rbase + r) * 256 + col] =
                __builtin_amdgcn_exp2f(acc[ns][r] * scale);
    }
}

// ---------------------------------------------------------------------------
// Segment flash partial, qtile=8, 4 waves.  NO-MAX softmax: scores are
// O(1)-bounded (sum w_h tanh, sum w^2 ~= 1), so e^s never overflows fp32;
// unshifted exp is mathematically identical softmax -> no per-row max
// reduction, no pM.  Masked keys -> e = 0 exactly.
// Latency plan: all 16 ek float4 prefetched before the staging barrier;
// all 16 v float4 issued right after the score loop (ek regs dead), hiding
// under shuffle-reduce + Ps write + barrier.  Per-block serial path ~2.5us
// (was ~12us inferred from round-1 occupancy counters).
// ---------------------------------------------------------------------------
__global__ __launch_bounds__(256, 3) void score_pv_seg4(
    const float* __restrict__ qp,      // [B*NQ, H]  EQ = exp2(q * 2/ln2)
    const float* __restrict__ kp,      // [B*NK, H]  EK = exp2(k * 2/ln2)
    const float* __restrict__ values,  // [B, NK, VD]
    const int*   __restrict__ vlens,   // [B]
    const float* __restrict__ w_v,     // [H]
    float* __restrict__ pO,            // [B][8qt][8seg][8q][256]
    float* __restrict__ pL)            // [B][8qt][8seg][8q]
{
    __shared__ float eq[8][260];
    __shared__ float wv[HD];
    __shared__ float Ps[8][66];
    __shared__ float part[4][8][260];

    const int b   = blockIdx.x & 15;
    const int qt  = blockIdx.x >> 4;    // 0..7
    const int seg = blockIdx.y;         // 0..7
    const int vl  = vlens[b];
    if (seg * 64 >= vl) return;

    const int t = threadIdx.x, lane = t & 63, wave = t >> 6;
    const int key = wave * 16 + (lane >> 2);   // 0..63
    const int ch  = lane & 3;
    const int kg  = seg * 64 + key;

    // ---- prefetch ALL 16 ek float4 (full H row of this key) ----
    const float* krow = kp + ((size_t)b * NK + kg) * HD + ch * 4;
    float4 ek[16];
    #pragma unroll
    for (int j = 0; j < 16; ++j) ek[j] = *(const float4*)&krow[j * 16];

    // ---- stage EQ (8 rows x 256) and w ----
    const float* qsrc = qp + ((size_t)b * NQ + qt * 8) * HD;
    #pragma unroll
    for (int i = 0; i < 2; ++i) {
        int idx = i * 256 + t;
        int row = idx >> 6, c4 = (idx & 63) * 4;
        *(float4*)&eq[row][c4] = *(const float4*)&qsrc[(size_t)row * HD + c4];
    }
    if (t < 64) *(float4*)&wv[t * 4] = *(const float4*)&w_v[t * 4];
    __syncthreads();

    // Wsum (redundant per wave, parallel)
    float Wsum;
    {
        float ws = wv[lane] + wv[lane + 64] + wv[lane + 128] + wv[lane + 192];
        #pragma unroll
        for (int off = 32; off; off >>= 1) ws += __shfl_xor(ws, off);
        Wsum = ws;
    }

    // ---- scores: 4-way grouped reciprocal, ek from regs ----
    float s[8] = {0.f, 0.f, 0.f, 0.f, 0.f, 0.f, 0.f, 0.f};
    #pragma unroll
    for (int j = 0; j < 16; ++j) {
        const int h = j * 16 + ch * 4;
        float4 e4 = ek[j];
        float4 w4 = *(const float4*)&wv[h];
        #pragma unroll
        for (int qi = 0; qi < 8; ++qi) {
            float4 q4 = *(const float4*)&eq[qi][h];   // LDS broadcast
            float p0 = fmaf(q4.x, e4.x, 1.f);
            float p1 = fmaf(q4.y, e4.y, 1.f);
            float p2 = fmaf(q4.z, e4.z, 1.f);
            float p3 = fmaf(q4.w, e4.w, 1.f);
            float d01 = p0 * p1;
            float d23 = p2 * p3;
            float n01 = fmaf(w4.x, p1, w4.y * p0);
            float n23 = fmaf(w4.z, p3, w4.w * p2);
            float num = fmaf(d01, n23, d23 * n01);
            float r   = __builtin_amdgcn_rcpf(d01 * d23);
            s[qi] = fmaf(num, r, s[qi]);
        }
    }

    // ---- issue V prefetch NOW (ek regs dead; latency hides under below) ----
    const float* vbase = values + ((size_t)b * NK + seg * 64 + wave * 16) * HD;
    float4 vv[16];
    #pragma unroll
    for (int i = 0; i < 16; ++i)
        vv[i] = *(const float4*)&vbase[(size_t)i * HD + lane * 4];

    // ---- combine ch halves, write Ps = e^{score} (no max shift) ----
    const float L2E = 1.4426950408889634f;
    #pragma unroll
    for (int qi = 0; qi < 8; ++qi) {
        s[qi] += __shfl_xor(s[qi], 1);
        s[qi] += __shfl_xor(s[qi], 2);
    }
    if (ch == 0) {
        const bool masked = (kg >= vl);
        #pragma unroll
        for (int qi = 0; qi < 8; ++qi) {
            float sv = fmaf(-2.f, s[qi], Wsum);       // score in [-~12, ~12]
            Ps[qi][key] = masked ? 0.f
                                 : __builtin_amdgcn_exp2f(sv * L2E);
        }
    }
    __syncthreads();

    // ---- PV: wave handles 16 keys x 8 q-rows; lane owns vd = lane*4 ----
    f32x4 acc[8];
    #pragma unroll
    for (int qi = 0; qi < 8; ++qi) acc[qi] = (f32x4){0.f, 0.f, 0.f, 0.f};
    #pragma unroll
    for (int i = 0; i < 16; ++i) {
        float4 v = vv[i];
        #pragma unroll
        for (int qi = 0; qi < 8; ++qi) {
            float p = Ps[qi][wave * 16 + i];          // LDS broadcast
            acc[qi][0] = fmaf(p, v.x, acc[qi][0]);
            acc[qi][1] = fmaf(p, v.y, acc[qi][1]);
            acc[qi][2] = fmaf(p, v.z, acc[qi][2]);
            acc[qi][3] = fmaf(p, v.w, acc[qi][3]);
        }
    }

    // ---- row sums l (Ps intact), rows wave*2, wave*2+1 ----
    #pragma unroll
    for (int r = 0; r < 2; ++r) {
        const int row = wave * 2 + r;
        float l = Ps[row][lane];
        #pragma unroll
        for (int off = 32; off; off >>= 1) l += __shfl_xor(l, off);
        if (lane == 0)
            pL[(((size_t)(b * 8 + qt) * 8 + seg)) * 8 + row] = l;
    }

    #pragma unroll
    for (int qi = 0; qi < 8; ++qi)
        *(f32x4*)&part[wave][qi][lane * 4] = acc[qi];
    __syncthreads();

    // ---- cross-wave reduce + store partials ----
    const size_t ob = (((size_t)(b * 8 + qt) * 8 + seg)) * 8 * 256;
    #pragma unroll
    for (int i = 0; i < 2; ++i) {
        int idx = i * 256 + t;
        int qi = idx >> 6, c4 = (idx & 63) * 4;
        float4 p0 = *(const float4*)&part[0][qi][c4];
        float4 p1 = *(const float4*)&part[1][qi][c4];
        float4 p2 = *(const float4*)&part[2][qi][c4];
        float4 p3 = *(const float4*)&part[3][qi][c4];
        float4 o;
        o.x = (p0.x + p1.x) + (p2.x + p3.x);
        o.y = (p0.y + p1.y) + (p2.y + p3.y);
        o.z = (p0.z + p1.z) + (p2.z + p3.z);
        o.w = (p0.w + p1.w) + (p2.w + p3.w);
        *(float4*)&pO[ob + (size_t)qi * 256 + c4] = o;
    }
}

// ---------------------------------------------------------------------------
// Combine (no-max): O = sum_i pO_i / sum_i pL_i, i < nc.  Pure adds + 1 rcp.
// ---------------------------------------------------------------------------
__global__ __launch_bounds__(256) void combine_seg3(
    const float* __restrict__ pO, const float* __restrict__ pL,
    const int* __restrict__ vlens, float* __restrict__ out)
{
    const int b  = blockIdx.x >> 6;
    const int q  = blockIdx.x & 63;
    const int t  = threadIdx.x;
    const int nc = (vlens[b] + 63) >> 6;
    const int qt = q >> 3, qi = q & 7;

    const size_t base = (size_t)(b * 8 + qt) * 8;

    float L = 0.f, acc = 0.f;
    #pragma unroll
    for (int i = 0; i < 8; ++i) {
        if (i < nc) {
            L   += pL[(base + i) * 8 + qi];
            acc += pO[((base + i) * 8 + qi) * 256 + t];
        }
    }
    out[((size_t)(b * 64 + q)) * 256 + t] = acc * __builtin_amdgcn_rcpf(L);
}

extern "C" void kernel_launch(void* const* d_in, const int* in_sizes, int n_in,
                              void* d_out, int out_size, void* d_ws, size_t ws_size,
                              hipStream_t stream) {
    const float* queries = (const float*)d_in[0];
    const float* keys    = (const float*)d_in[1];
    const float* values  = (const float*)d_in[2];
    const int*   vlens   = (const int*)d_in[3];
    const float* W_q     = (const float*)d_in[4];
    const float* W_k     = (const float*)d_in[5];
    const float* w_v     = (const float*)d_in[6];
    float* out = (float*)d_out;

    // ws layout (~17.5 MB of 256 MiB):
    float*  kp  = (float*)d_ws;                          // 8 MB
    float*  qp  = kp + (size_t)BB * NK * HD;             // 1 MB
    float*  pO  = qp + (size_t)BB * NQ * HD;             // 8 MB
    float*  pL  = pO + (size_t)BB * 8 * 8 * 8 * 256;     // 32 KB
    ushort* wqh = (ushort*)(pL + (size_t)BB * 8 * 8 * 8);
    ushort* wql = wqh + 65536;
    ushort* wkh = wql + 65536;
    ushort* wkl = wkh + 65536;

    const float SC = 2.885390081777927f;                 // 2/ln(2)

    wconv<<<dim3(128), 256, 0, stream>>>(W_q, W_k, wqh, wql, wkh, wkl);
    proj_fused<<<dim3(144, 4), 256, 0, stream>>>(queries, keys,
                                                 wqh, wql, wkh, wkl,
                                                 qp, kp, SC);
    score_pv_seg4<<<dim3(128, 8), 256, 0, stream>>>(qp, kp, values, vlens, w_v,
                                                    pO, pL);
    combine_seg3<<<dim3(BB * NQ), 256, 0, stream>>>(pO, pL, vlens, out);
}

// Round 4
// 110.408 us; speedup vs baseline: 1.0933x; 1.0933x over previous
//
#include <hip/hip_runtime.h>
#include <hip/hip_bf16.h>

#define BB 16
#define NQ 64
#define NK 512
#define HD 256   // H = QS = KS = VD = 256

typedef __attribute__((ext_vector_type(8))) short short8;
typedef __attribute__((ext_vector_type(4))) float f32x4;

__device__ __forceinline__ ushort bf16_rne(float v) {
    unsigned u = __float_as_uint(v);
    return (ushort)((u + 0x7FFFu + ((u >> 16) & 1u)) >> 16);
}
__device__ __forceinline__ float bf16_to_f(ushort h) {
    return __uint_as_float(((unsigned)h) << 16);
}

// ---------------------------------------------------------------------------
// W-only conversion (tiny): W fp32 [k][n] -> hi/lo bf16 TRANSPOSED [n][k].
// ---------------------------------------------------------------------------
__global__ __launch_bounds__(256) void wconv(
    const float* __restrict__ wq, const float* __restrict__ wk,
    ushort* __restrict__ wqh, ushort* __restrict__ wql,
    ushort* __restrict__ wkh, ushort* __restrict__ wkl)
{
    int widx = blockIdx.x * 256 + threadIdx.x;     // 0..32767
    const float* W; ushort *wh, *wl;
    if (widx < 16384) { W = wq; wh = wqh; wl = wql; }
    else { W = wk; wh = wkh; wl = wkl; widx -= 16384; }
    int n  = widx >> 6;
    int k4 = (widx & 63) * 4;
    ushort hh[4], ll[4];
    #pragma unroll
    for (int c = 0; c < 4; ++c) {
        float v = W[(k4 + c) * 256 + n];
        hh[c] = bf16_rne(v);
        ll[c] = bf16_rne(v - bf16_to_f(hh[c]));
    }
    *(ushort4*)&wh[n * 256 + k4] = make_ushort4(hh[0], hh[1], hh[2], hh[3]);
    *(ushort4*)&wl[n * 256 + k4] = make_ushort4(ll[0], ll[1], ll[2], ll[3]);
}

// ---------------------------------------------------------------------------
// Projection GEMM with FUSED A-conversion (unchanged).
// epilogue: exp2(acc*scale) so score kernel consumes EQ=e^{2q}, EK=e^{2k}.
// ---------------------------------------------------------------------------
__global__ __launch_bounds__(256, 2) void proj_fused(
    const float* __restrict__ queries, const float* __restrict__ keys,
    const ushort* __restrict__ wqh, const ushort* __restrict__ wql,
    const ushort* __restrict__ wkh, const ushort* __restrict__ wkl,
    float* __restrict__ qp, float* __restrict__ kp, float scale)
{
    __shared__ ushort AsH[64 * 64], AsL[64 * 64];
    __shared__ ushort BsH[64 * 64], BsL[64 * 64];

    const float* A; const ushort *Bh, *Bl; float* C; int rows0;
    const int bx = blockIdx.x;
    if (bx < 16) { A = queries; Bh = wqh; Bl = wql; C = qp; rows0 = bx * 64; }
    else         { A = keys;    Bh = wkh; Bl = wkl; C = kp; rows0 = (bx - 16) * 64; }
    const int cols0 = blockIdx.y * 64;

    const int t = threadIdx.x, lane = t & 63, wave = t >> 6;
    const int quad = lane >> 4, l15 = lane & 15;
    const int sr  = t >> 2;
    const int sc2 = (t & 3) * 2;

    f32x4 acc[4];
    #pragma unroll
    for (int j = 0; j < 4; ++j) acc[j] = (f32x4){0.f, 0.f, 0.f, 0.f};

    for (int k0 = 0; k0 < 256; k0 += 64) {
        const float* arow = &A[(size_t)(rows0 + sr) * 256 + k0 + sc2 * 8];
        float4 a0 = *(const float4*)&arow[0];
        float4 a1 = *(const float4*)&arow[4];
        float4 a2 = *(const float4*)&arow[8];
        float4 a3 = *(const float4*)&arow[12];
        const ushort* bhp = &Bh[(size_t)(cols0 + sr) * 256 + k0 + sc2 * 8];
        const ushort* blp = &Bl[(size_t)(cols0 + sr) * 256 + k0 + sc2 * 8];
        short8 b0h = *(const short8*)&bhp[0];
        short8 b1h = *(const short8*)&bhp[8];
        short8 b0l = *(const short8*)&blp[0];
        short8 b1l = *(const short8*)&blp[8];

        __syncthreads();

        float av[16] = {a0.x, a0.y, a0.z, a0.w, a1.x, a1.y, a1.z, a1.w,
                        a2.x, a2.y, a2.z, a2.w, a3.x, a3.y, a3.z, a3.w};
        short8 ah0, ah1, al0, al1;
        #pragma unroll
        for (int e = 0; e < 8; ++e) {
            ushort h0 = bf16_rne(av[e]);
            ushort h1 = bf16_rne(av[8 + e]);
            ah0[e] = (short)h0;
            ah1[e] = (short)h1;
            al0[e] = (short)bf16_rne(av[e] - bf16_to_f(h0));
            al1[e] = (short)bf16_rne(av[8 + e] - bf16_to_f(h1));
        }
        {
            int s0 = sr * 8 + ((sc2 + 0) ^ (sr & 7));
            int s1 = sr * 8 + ((sc2 + 1) ^ (sr & 7));
            *(short8*)&AsH[s0 * 8] = ah0;
            *(short8*)&AsH[s1 * 8] = ah1;
            *(short8*)&AsL[s0 * 8] = al0;
            *(short8*)&AsL[s1 * 8] = al1;
            *(short8*)&BsH[s0 * 8] = b0h;
            *(short8*)&BsH[s1 * 8] = b1h;
            *(short8*)&BsL[s0 * 8] = b0l;
            *(short8*)&BsL[s1 * 8] = b1l;
        }
        __syncthreads();

        #pragma unroll
        for (int ks = 0; ks < 2; ++ks) {
            const int c = ks * 4 + quad;
            short8 aH, aL, bH[4], bL[4];
            {
                int r = wave * 16 + l15;
                int slot = r * 8 + (c ^ (r & 7));
                aH = *(const short8*)&AsH[slot * 8];
                aL = *(const short8*)&AsL[slot * 8];
            }
            #pragma unroll
            for (int ns = 0; ns < 4; ++ns) {
                int n = ns * 16 + l15;
                int slot = n * 8 + (c ^ (n & 7));
                bH[ns] = *(const short8*)&BsH[slot * 8];
                bL[ns] = *(const short8*)&BsL[slot * 8];
            }
            #pragma unroll
            for (int ns = 0; ns < 4; ++ns)
                acc[ns] = __builtin_amdgcn_mfma_f32_16x16x32_bf16(aH, bH[ns], acc[ns], 0, 0, 0);
            #pragma unroll
            for (int ns = 0; ns < 4; ++ns)
                acc[ns] = __builtin_amdgcn_mfma_f32_16x16x32_bf16(aL, bH[ns], acc[ns], 0, 0, 0);
            #pragma unroll
            for (int ns = 0; ns < 4; ++ns)
                acc[ns] = __builtin_amdgcn_mfma_f32_16x16x32_bf16(aH, bL[ns], acc[ns], 0, 0, 0);
        }
    }

    const int rbase = rows0 + wave * 16 + quad * 4;
    #pragma unroll
    for (int ns = 0; ns < 4; ++ns) {
        int col = cols0 + ns * 16 + l15;
        #pragma unroll
        for (int r = 0; r < 4; ++r)
            C[(size_t)(rbase + r) * 256 + col] =
                __builtin_amdgcn_exp2f(acc[ns][r] * scale);
    }
}

// ---------------------------------------------------------------------------
// Segment flash partial, qtile=8, 8 waves = (kq, hh) key-quarter x h-half
// (round-2's measured-best skeleton) + no-max softmax + PV depth-4 v ring.
// __launch_bounds__(512,6): VGPR cap ~85 -> 6 waves/SIMD -> 3 blocks/CU,
// matching the 45.7 KB LDS limit.  No-max: |score| <= ||w||_1 ~ 13 so
// unshifted e^s cannot overflow fp32; masked keys get exactly 0.
// ---------------------------------------------------------------------------
__global__ __launch_bounds__(512, 6) void score_pv_seg5(
    const float* __restrict__ qp,      // [B*NQ, H]  EQ = exp2(q * 2/ln2)
    const float* __restrict__ kp,      // [B*NK, H]  EK = exp2(k * 2/ln2)
    const float* __restrict__ values,  // [B, NK, VD]
    const int*   __restrict__ vlens,   // [B]
    const float* __restrict__ w_v,     // [H]
    float* __restrict__ pO,            // [B][8qt][8seg][8q][256]
    float* __restrict__ pL)            // [B][8qt][8seg][8q]
{
    __shared__ float eq[8][260];
    __shared__ float wv[HD];
    __shared__ float Ps[8][66];
    __shared__ float sP[8][66];
    __shared__ float part[4][8][260];

    const int b   = blockIdx.x & 15;
    const int qt  = blockIdx.x >> 4;    // 0..7
    const int seg = blockIdx.y;         // 0..7
    const int vl  = vlens[b];
    if (seg * 64 >= vl) return;

    const int t = threadIdx.x, lane = t & 63, wave = t >> 6;  // wave 0..7
    const int kq = wave & 3;            // key quarter
    const int hh = wave >> 2;           // h half
    const int key = kq * 16 + (lane >> 2);   // 0..63
    const int ch  = lane & 3;
    const int kg  = seg * 64 + key;

    // ---- issue this wave's 8 ek loads (latency overlaps eq staging) ----
    const float* krow = kp + ((size_t)b * NK + kg) * HD + hh * 128 + ch * 4;
    float4 ek[8];
    #pragma unroll
    for (int j = 0; j < 8; ++j) ek[j] = *(const float4*)&krow[j * 16];

    // ---- stage EQ (8 rows x 256): exactly one float4 per thread ----
    const float* qsrc = qp + ((size_t)b * NQ + qt * 8) * HD;
    {
        int row = t >> 6, c4 = (t & 63) * 4;
        *(float4*)&eq[row][c4] = *(const float4*)&qsrc[(size_t)row * HD + c4];
    }
    if (t < 64) *(float4*)&wv[t * 4] = *(const float4*)&w_v[t * 4];
    __syncthreads();

    // Wsum (redundant per wave, parallel)
    float Wsum;
    {
        float ws = wv[lane] + wv[lane + 64] + wv[lane + 128] + wv[lane + 192];
        #pragma unroll
        for (int off = 32; off; off >>= 1) ws += __shfl_xor(ws, off);
        Wsum = ws;
    }

    // ---- scores over this wave's h-half: 4-way grouped reciprocal ----
    float s[8] = {0.f, 0.f, 0.f, 0.f, 0.f, 0.f, 0.f, 0.f};
    #pragma unroll
    for (int j = 0; j < 8; ++j) {
        const int h = hh * 128 + j * 16 + ch * 4;
        float4 e4 = ek[j];
        float4 w4 = *(const float4*)&wv[h];
        #pragma unroll
        for (int qi = 0; qi < 8; ++qi) {
            float4 q4 = *(const float4*)&eq[qi][h];   // LDS broadcast (EQ)
            float p0 = fmaf(q4.x, e4.x, 1.f);
            float p1 = fmaf(q4.y, e4.y, 1.f);
            float p2 = fmaf(q4.z, e4.z, 1.f);
            float p3 = fmaf(q4.w, e4.w, 1.f);
            float d01 = p0 * p1;
            float d23 = p2 * p3;
            float n01 = fmaf(w4.x, p1, w4.y * p0);
            float n23 = fmaf(w4.z, p3, w4.w * p2);
            float num = fmaf(d01, n23, d23 * n01);
            float r   = __builtin_amdgcn_rcpf(d01 * d23);
            s[qi] = fmaf(num, r, s[qi]);
        }
    }
    #pragma unroll
    for (int qi = 0; qi < 8; ++qi) {
        s[qi] += __shfl_xor(s[qi], 1);
        s[qi] += __shfl_xor(s[qi], 2);
    }
    if (hh == 1 && ch == 0) {
        #pragma unroll
        for (int qi = 0; qi < 8; ++qi) sP[qi][key] = s[qi];
    }
    __syncthreads();
    // ---- no-max: Ps = e^{score} directly; masked -> exact 0 ----
    const float L2E = 1.4426950408889634f;
    if (hh == 0 && ch == 0) {
        const bool masked = (kg >= vl);
        #pragma unroll
        for (int qi = 0; qi < 8; ++qi) {
            float sv = fmaf(-2.f, s[qi] + sP[qi][key], Wsum);
            Ps[qi][key] = masked ? 0.f : __builtin_amdgcn_exp2f(sv * L2E);
        }
    }
    __syncthreads();

    // ---- issue first 4 v loads; their latency hides under the pL reduce ----
    const float* vbase = values + ((size_t)b * NK + seg * 64 + kq * 16) * HD;
    float4 vv[4];
    #pragma unroll
    for (int i = 0; i < 4; ++i)
        vv[i] = *(const float4*)&vbase[(size_t)i * HD + lane * 4];

    // ---- pL row sums: wave w reduces row w ----
    {
        float l = Ps[wave][lane];
        #pragma unroll
        for (int off = 32; off; off >>= 1) l += __shfl_xor(l, off);
        if (lane == 0)
            pL[(((size_t)(b * 8 + qt) * 8 + seg)) * 8 + wave] = l;
    }

    // ---- PV: wave (kq,hh) -> 16 keys x 4 q-rows; depth-4 v ring ----
    f32x4 acc[4];
    #pragma unroll
    for (int r = 0; r < 4; ++r) acc[r] = (f32x4){0.f, 0.f, 0.f, 0.f};
    #pragma unroll
    for (int i = 0; i < 16; ++i) {
        float4 v = vv[i & 3];
        if (i + 4 < 16)
            vv[i & 3] = *(const float4*)&vbase[(size_t)(i + 4) * HD + lane * 4];
        #pragma unroll
        for (int r = 0; r < 4; ++r) {
            float p = Ps[hh * 4 + r][kq * 16 + i];    // LDS broadcast
            acc[r][0] = fmaf(p, v.x, acc[r][0]);
            acc[r][1] = fmaf(p, v.y, acc[r][1]);
            acc[r][2] = fmaf(p, v.z, acc[r][2]);
            acc[r][3] = fmaf(p, v.w, acc[r][3]);
        }
    }
    #pragma unroll
    for (int r = 0; r < 4; ++r)
        *(f32x4*)&part[kq][hh * 4 + r][lane * 4] = acc[r];
    __syncthreads();

    // ---- cross-wave reduce + store partials (512 thr, one float4 each) ----
    const size_t ob = (((size_t)(b * 8 + qt) * 8 + seg)) * 8 * 256;
    {
        int qi = t >> 6, c4 = (t & 63) * 4;
        float4 p0 = *(const float4*)&part[0][qi][c4];
        float4 p1 = *(const float4*)&part[1][qi][c4];
        float4 p2 = *(const float4*)&part[2][qi][c4];
        float4 p3 = *(const float4*)&part[3][qi][c4];
        float4 o;
        o.x = (p0.x + p1.x) + (p2.x + p3.x);
        o.y = (p0.y + p1.y) + (p2.y + p3.y);
        o.z = (p0.z + p1.z) + (p2.z + p3.z);
        o.w = (p0.w + p1.w) + (p2.w + p3.w);
        *(float4*)&pO[ob + (size_t)qi * 256 + c4] = o;
    }
}

// ---------------------------------------------------------------------------
// Combine (no-max): O = sum_i pO_i / sum_i pL_i, i < nc.  Pure adds + 1 rcp.
// ---------------------------------------------------------------------------
__global__ __launch_bounds__(256) void combine_seg3(
    const float* __restrict__ pO, const float* __restrict__ pL,
    const int* __restrict__ vlens, float* __restrict__ out)
{
    const int b  = blockIdx.x >> 6;
    const int q  = blockIdx.x & 63;
    const int t  = threadIdx.x;
    const int nc = (vlens[b] + 63) >> 6;
    const int qt = q >> 3, qi = q & 7;

    const size_t base = (size_t)(b * 8 + qt) * 8;

    float L = 0.f, acc = 0.f;
    #pragma unroll
    for (int i = 0; i < 8; ++i) {
        if (i < nc) {
            L   += pL[(base + i) * 8 + qi];
            acc += pO[((base + i) * 8 + qi) * 256 + t];
        }
    }
    out[((size_t)(b * 64 + q)) * 256 + t] = acc * __builtin_amdgcn_rcpf(L);
}

extern "C" void kernel_launch(void* const* d_in, const int* in_sizes, int n_in,
                              void* d_out, int out_size, void* d_ws, size_t ws_size,
                              hipStream_t stream) {
    const float* queries = (const float*)d_in[0];
    const float* keys    = (const float*)d_in[1];
    const float* values  = (const float*)d_in[2];
    const int*   vlens   = (const int*)d_in[3];
    const float* W_q     = (const float*)d_in[4];
    const float* W_k     = (const float*)d_in[5];
    const float* w_v     = (const float*)d_in[6];
    float* out = (float*)d_out;

    // ws layout (~17.5 MB of 256 MiB):
    float*  kp  = (float*)d_ws;                          // 8 MB
    float*  qp  = kp + (size_t)BB * NK * HD;             // 1 MB
    float*  pO  = qp + (size_t)BB * NQ * HD;             // 8 MB
    float*  pL  = pO + (size_t)BB * 8 * 8 * 8 * 256;     // 32 KB
    ushort* wqh = (ushort*)(pL + (size_t)BB * 8 * 8 * 8);
    ushort* wql = wqh + 65536;
    ushort* wkh = wql + 65536;
    ushort* wkl = wkh + 65536;

    const float SC = 2.885390081777927f;                 // 2/ln(2)

    wconv<<<dim3(128), 256, 0, stream>>>(W_q, W_k, wqh, wql, wkh, wkl);
    proj_fused<<<dim3(144, 4), 256, 0, stream>>>(queries, keys,
                                                 wqh, wql, wkh, wkl,
                                                 qp, kp, SC);
    score_pv_seg5<<<dim3(128, 8), 512, 0, stream>>>(qp, kp, values, vlens, w_v,
                                                    pO, pL);
    combine_seg3<<<dim3(BB * NQ), 256, 0, stream>>>(pO, pL, vlens, out);
}